// Round 2
// baseline (3009.722 us; speedup 1.0000x reference)
//
#include <hip/hip_runtime.h>

// ---------- types & helpers ----------
typedef __attribute__((ext_vector_type(8))) short bf16x8;
typedef __attribute__((ext_vector_type(8))) unsigned short ushort8;
typedef __attribute__((ext_vector_type(4))) float f32x4;

__device__ __forceinline__ unsigned short f2bf(float f) {
  union { float f; unsigned u; } v; v.f = f;
  unsigned r = (v.u + 0x7FFFu + ((v.u >> 16) & 1u)) >> 16;
  return (unsigned short)r;
}
__device__ __forceinline__ float bf2f(unsigned short h) {
  union { unsigned u; float f; } v; v.u = ((unsigned)h) << 16;
  return v.f;
}
__device__ __forceinline__ float sigm(float x) { return 1.f / (1.f + __expf(-x)); }
__device__ __forceinline__ float tanh_(float x) { return 1.f - 2.f / (__expf(2.f * x) + 1.f); }

#define GLDS(g, l) __builtin_amdgcn_global_load_lds( \
    (const __attribute__((address_space(1))) unsigned int*)(g), \
    (__attribute__((address_space(3))) unsigned int*)(l), 16, 0, 0)

// ---------- fp32 -> bf16 conversion (vectorized) ----------
__global__ void conv_bf16(const float* __restrict__ src, unsigned short* __restrict__ dst, int n4) {
  int i = blockIdx.x * blockDim.x + threadIdx.x;
  if (i >= n4) return;
  const float4 v = ((const float4*)src)[i];
  ushort4 o; o.x = f2bf(v.x); o.y = f2bf(v.y); o.z = f2bf(v.z); o.w = f2bf(v.w);
  ((ushort4*)dst)[i] = o;
}

// ---------- embedding gather -> bf16 [4096][512] ----------
__global__ void gather_xe(const int* __restrict__ x, const float* __restrict__ emb,
                          unsigned short* __restrict__ xe) {
  const int m = blockIdx.x;              // b*256 + t
  const int tok = x[m];
  const float4 v = ((const float4*)(emb + (size_t)tok * 512))[threadIdx.x];
  ushort4 o; o.x = f2bf(v.x); o.y = f2bf(v.y); o.z = f2bf(v.z); o.w = f2bf(v.w);
  ((ushort4*)(xe + (size_t)m * 512))[threadIdx.x] = o;
}

// ---------- h0 = tanh(z @ W_init^T + b_init) -> hgf parity 0 (fp32) ----------
__global__ __launch_bounds__(256) void h0_kernel(const float* __restrict__ z,
                                                 const float* __restrict__ Wi,
                                                 const float* __restrict__ bi,
                                                 float* __restrict__ hgf) {
  const int idx = blockIdx.x * 256 + threadIdx.x;  // 0..16383
  const int b = idx & 15, i = idx >> 4;
  const float4* wr = (const float4*)(Wi + (size_t)i * 1024);
  const float4* zr = (const float4*)(z + (size_t)b * 1024);
  float acc = bi[i];
#pragma unroll 4
  for (int k = 0; k < 256; ++k) {
    float4 w = wr[k], zv = zr[k];
    acc += w.x * zv.x + w.y * zv.y + w.z * zv.z + w.w * zv.w;
  }
  hgf[(size_t)b * 1024 + i] = tanh_(acc);
}

// ---------- bf16 GEMM, C[M,N] = A[M,K] @ B[N,K]^T + bias ----------
template <typename OutT>
__global__ __launch_bounds__(256) void gemm_bt(
    const unsigned short* __restrict__ A, const unsigned short* __restrict__ Bm,
    const float* __restrict__ bias, OutT* __restrict__ C,
    int M, int N, int K) {
  __shared__ __align__(16) unsigned short As[128 * 32];
  __shared__ __align__(16) unsigned short Bs[128 * 32];
  const int tid = threadIdx.x;
  const int lane = tid & 63, wave = tid >> 6;
  const int nTM = M >> 7;
  const int bm = blockIdx.x % nTM, bn = blockIdx.x / nTM;
  const long row0 = (long)bm << 7, col0 = (long)bn << 7;
  const int wm = (wave & 1) << 6, wn = (wave >> 1) << 6;

  f32x4 acc[4][4] = {};

  const int sr = (wave << 4) + (lane >> 2);
  const int sk = (lane & 3) << 3;
  const unsigned short* Abase = A + ((size_t)(row0 + sr)) * K + sk;
  const unsigned short* Bbase = Bm + ((size_t)(col0 + sr)) * K + sk;
  char* ldsA = (char*)As + wave * 1024;
  char* ldsB = (char*)Bs + wave * 1024;

  for (int k0 = 0; k0 < K; k0 += 32) {
    __syncthreads();
    GLDS(Abase + k0, ldsA);
    GLDS(Abase + (size_t)64 * K + k0, ldsA + 4096);
    GLDS(Bbase + k0, ldsB);
    GLDS(Bbase + (size_t)64 * K + k0, ldsB + 4096);
    __syncthreads();
    const int lr = lane & 15, lk = (lane >> 4) << 3;
    bf16x8 af[4], bfr[4];
#pragma unroll
    for (int i = 0; i < 4; ++i) {
      af[i]  = *(const bf16x8*)(As + (wm + i * 16 + lr) * 32 + lk);
      bfr[i] = *(const bf16x8*)(Bs + (wn + i * 16 + lr) * 32 + lk);
    }
#pragma unroll
    for (int i = 0; i < 4; ++i)
#pragma unroll
      for (int j = 0; j < 4; ++j)
        acc[i][j] = __builtin_amdgcn_mfma_f32_16x16x32_bf16(af[i], bfr[j], acc[i][j], 0, 0, 0);
  }

  const int lr = lane & 15, lq = (lane >> 4) << 2;
#pragma unroll
  for (int i = 0; i < 4; ++i) {
#pragma unroll
    for (int q = 0; q < 4; ++q) {
      const long r = row0 + wm + i * 16 + lq + q;
      OutT* crow = C + (size_t)r * N;
#pragma unroll
      for (int j = 0; j < 4; ++j) {
        const long cc = col0 + wn + j * 16 + lr;
        float v = acc[i][j][q] + bias[cc];
        if constexpr (sizeof(OutT) == 2) crow[cc] = (OutT)f2bf(v);
        else                             crow[cc] = (OutT)v;
      }
    }
  }
}

// ---------- persistent GRU recurrence (agent-coherent exchange, no threadfence) ----------
// 64 blocks x 256 thr. Block j owns h cols [16j,16j+16): 48 W_hh rows held in
// REGISTERS (bf16 fragments, loaded once). Per step: gh = h @ Wslice^T via MFMA
// (A = h loaded as fp32 agent-scope atomics from parity buffer, K split 4 waves),
// LDS reduce, gates in fp32 regs, agent-scope h store, per-block release flag.
__global__ __launch_bounds__(256) void gru_rec(
    const float* __restrict__ Whh, const float* __restrict__ bhh,
    const unsigned short* __restrict__ gi,
    float* __restrict__ hgf, unsigned short* __restrict__ hs,
    unsigned int* __restrict__ flags) {
  __shared__ float ghp[4][16][48];                        // 12 KB partials
  const int tid = threadIdx.x, lane = tid & 63, wave = tid >> 6;
  const int j = blockIdx.x;

  const int lr = lane & 15;            // A row (batch) / B row-within-tile
  const int hi8 = (lane >> 4) << 3;    // k-octet offset
  const int kw = wave << 8;            // 256 k per wave

  // ---- load W_hh slice into registers (bf16 fragments), once ----
  bf16x8 wf[3][8];
#pragma unroll
  for (int n = 0; n < 3; ++n) {
    const float* wrow = Whh + (size_t)(n * 1024 + (j << 4) + lr) * 1024 + kw + hi8;
#pragma unroll
    for (int ki = 0; ki < 8; ++ki) {
      const float4 u = *(const float4*)(wrow + ki * 32);
      const float4 v = *(const float4*)(wrow + ki * 32 + 4);
      bf16x8 w;
      w[0] = (short)f2bf(u.x); w[1] = (short)f2bf(u.y);
      w[2] = (short)f2bf(u.z); w[3] = (short)f2bf(u.w);
      w[4] = (short)f2bf(v.x); w[5] = (short)f2bf(v.y);
      w[6] = (short)f2bf(v.z); w[7] = (short)f2bf(v.w);
      wf[n][ki] = w;
    }
  }

  const int b = tid >> 4, c = tid & 15;
  const int cg = (j << 4) + c;
  float hreg = hgf[(size_t)b * 1024 + cg];   // h0 (parity 0, plain load: kernel boundary)
  const float br = bhh[cg], bz = bhh[1024 + cg], bn = bhh[2048 + cg];

  // prefetch gi for t=0
  const unsigned short* gr0 = gi + ((size_t)b * 256 + 0) * 3072;
  float ir = bf2f(gr0[cg]), iz = bf2f(gr0[1024 + cg]), inn = bf2f(gr0[2048 + cg]);

  for (int t = 0; t < 256; ++t) {
    if (t > 0) {
      if (tid < 64) {
        const unsigned tgt = (unsigned)t;
        long guard = 0;
        while (__hip_atomic_load(&flags[tid << 5], __ATOMIC_RELAXED, __HIP_MEMORY_SCOPE_AGENT) < tgt) {
          __builtin_amdgcn_s_sleep(1);
          if (++guard > (1L << 20)) break;   // hang guard (never hit if co-resident)
        }
      }
      __syncthreads();
    }

    // ---- gh partials: acc[n] += h_frag * w_frag, K slice [kw, kw+256) ----
    const float* hb = hgf + ((t & 1) << 14);
    f32x4 acc[3] = {};
#pragma unroll
    for (int ki = 0; ki < 8; ++ki) {
      float* hp = (float*)(hb + (size_t)lr * 1024 + kw + (ki << 5) + hi8);
      float a[8];
#pragma unroll
      for (int e = 0; e < 8; ++e)
        a[e] = __hip_atomic_load(hp + e, __ATOMIC_RELAXED, __HIP_MEMORY_SCOPE_AGENT);
      bf16x8 af;
#pragma unroll
      for (int e = 0; e < 8; ++e) af[e] = (short)f2bf(a[e]);
#pragma unroll
      for (int n = 0; n < 3; ++n)
        acc[n] = __builtin_amdgcn_mfma_f32_16x16x32_bf16(af, wf[n][ki], acc[n], 0, 0, 0);
    }
#pragma unroll
    for (int n = 0; n < 3; ++n)
#pragma unroll
      for (int q = 0; q < 4; ++q)
        ghp[wave][(lane >> 4) * 4 + q][n * 16 + lr] = acc[n][q];
    __syncthreads();

    // ---- gates (all 256 threads: thread = (b,c)) ----
    const float hr = ghp[0][b][c]      + ghp[1][b][c]      + ghp[2][b][c]      + ghp[3][b][c];
    const float hz = ghp[0][b][16 + c] + ghp[1][b][16 + c] + ghp[2][b][16 + c] + ghp[3][b][16 + c];
    const float hn = ghp[0][b][32 + c] + ghp[1][b][32 + c] + ghp[2][b][32 + c] + ghp[3][b][32 + c];
    const float rg = sigm(ir + hr + br);
    const float zg = sigm(iz + hz + bz);
    const float ng = tanh_(inn + rg * (hn + bn));
    const float hprev = hreg;
    hreg = (1.f - zg) * ng + zg * hprev;

    if (t < 255) {
      __hip_atomic_store(&hgf[(((t + 1) & 1) << 14) + b * 1024 + cg], hreg,
                         __ATOMIC_RELAXED, __HIP_MEMORY_SCOPE_AGENT);
      __syncthreads();   // drains vmcnt: all waves' agent stores at coherence point
      if (tid == 0)
        __hip_atomic_store(&flags[j << 5], (unsigned)(t + 1),
                           __ATOMIC_RELEASE, __HIP_MEMORY_SCOPE_AGENT);
    }

    // off critical path: output h_t, prefetch gi for t+1
    hs[((size_t)b * 256 + t) * 1024 + cg] = f2bf(hprev);
    if (t < 255) {
      const unsigned short* gr = gi + ((size_t)b * 256 + (t + 1)) * 3072;
      ir = bf2f(gr[cg]); iz = bf2f(gr[1024 + cg]); inn = bf2f(gr[2048 + cg]);
    }
  }
}

// ---------- launch ----------
extern "C" void kernel_launch(void* const* d_in, const int* in_sizes, int n_in,
                              void* d_out, int out_size, void* d_ws, size_t ws_size,
                              hipStream_t stream) {
  const float* z     = (const float*)d_in[0];
  const int*   x     = (const int*)d_in[1];
  const float* emb   = (const float*)d_in[2];
  const float* Winit = (const float*)d_in[3];
  const float* binit = (const float*)d_in[4];
  const float* Wih   = (const float*)d_in[5];
  const float* Whh   = (const float*)d_in[6];
  const float* bih   = (const float*)d_in[7];
  const float* bhh   = (const float*)d_in[8];
  const float* Wout  = (const float*)d_in[9];
  const float* bout  = (const float*)d_in[10];
  float* out = (float*)d_out;

  char* ws = (char*)d_ws;
  size_t off = 0;
  auto alloc = [&](size_t bytes) { void* p = ws + off; off += (bytes + 255) & ~(size_t)255; return p; };
  unsigned int*   flags = (unsigned int*)alloc(64 * 128);
  unsigned short* xe    = (unsigned short*)alloc((size_t)4096 * 512 * 2);
  unsigned short* WihB  = (unsigned short*)alloc((size_t)3072 * 512 * 2);
  unsigned short* WoutB = (unsigned short*)alloc((size_t)32000 * 1024 * 2);
  unsigned short* giB   = (unsigned short*)alloc((size_t)4096 * 3072 * 2);
  unsigned short* hsB   = (unsigned short*)alloc((size_t)4096 * 1024 * 2);
  float*          hgf   = (float*)alloc((size_t)2 * 16 * 1024 * 4);
  (void)ws_size; (void)in_sizes; (void)n_in; (void)out_size;

  hipMemsetAsync(flags, 0, 64 * 128, stream);

  // weight conversions
  conv_bf16<<<dim3((3072 * 512 / 4 + 255) / 256), 256, 0, stream>>>(Wih, WihB, 3072 * 512 / 4);
  conv_bf16<<<dim3((32000 * 1024 / 4 + 255) / 256), 256, 0, stream>>>(Wout, WoutB, 32000 * 1024 / 4);

  // embeddings + h0
  gather_xe<<<dim3(4096), 128, 0, stream>>>(x, emb, xe);
  h0_kernel<<<dim3(64), 256, 0, stream>>>(z, Winit, binit, hgf);

  // gi = xe @ W_ih^T + b_ih   [4096, 3072] bf16
  gemm_bt<unsigned short><<<dim3(32 * 24), 256, 0, stream>>>(xe, WihB, bih, giB, 4096, 3072, 512);

  // GRU recurrence -> hs [4096, 1024] bf16
  gru_rec<<<dim3(64), 256, 0, stream>>>(Whh, bhh, giB, hgf, hsB, flags);

  // logits = hs @ W_out^T + b_out  [4096, 32000] fp32
  gemm_bt<float><<<dim3(32 * 250), 256, 0, stream>>>(hsB, WoutB, bout, out, 4096, 32000, 1024);
}

// Round 3
// 1278.454 us; speedup vs baseline: 2.3542x; 2.3542x over previous
//
#include <hip/hip_runtime.h>

// ---------- types & helpers ----------
typedef __attribute__((ext_vector_type(8))) short bf16x8;
typedef __attribute__((ext_vector_type(8))) unsigned short ushort8;
typedef __attribute__((ext_vector_type(4))) float f32x4;
typedef __attribute__((ext_vector_type(4))) int i32x4;

__device__ __forceinline__ unsigned short f2bf(float f) {
  union { float f; unsigned u; } v; v.f = f;
  unsigned r = (v.u + 0x7FFFu + ((v.u >> 16) & 1u)) >> 16;
  return (unsigned short)r;
}
__device__ __forceinline__ float bf2f(unsigned short h) {
  union { unsigned u; float f; } v; v.u = ((unsigned)h) << 16;
  return v.f;
}
__device__ __forceinline__ float sigm(float x) { return 1.f / (1.f + __expf(-x)); }
__device__ __forceinline__ float tanh_(float x) { return 1.f - 2.f / (__expf(2.f * x) + 1.f); }

// agent-coherent wide ops: bypass non-coherent per-XCD L2 (sc0 sc1), plain
// read/write path (NOT atomic path), no compiler fences (no buffer_wbl2/inv).
__device__ __forceinline__ i32x4 ld_coh_b128(const void* p) {
  i32x4 r;
  asm volatile("global_load_dwordx4 %0, %1, off sc0 sc1" : "=v"(r) : "v"(p) : "memory");
  return r;
}
__device__ __forceinline__ void st_coh_b128(void* p, i32x4 v) {
  asm volatile("global_store_dwordx4 %0, %1, off sc0 sc1" :: "v"(p), "v"(v) : "memory");
}
__device__ __forceinline__ void wait_vm0_fence() {
  asm volatile("s_waitcnt vmcnt(0)" ::: "memory");
  __builtin_amdgcn_sched_barrier(0);   // rule #18: don't let MFMA hoist past asm waitcnt
}

#define GLDS(g, l) __builtin_amdgcn_global_load_lds( \
    (const __attribute__((address_space(1))) unsigned int*)(g), \
    (__attribute__((address_space(3))) unsigned int*)(l), 16, 0, 0)

// ---------- fp32 -> bf16 conversion (vectorized) ----------
__global__ void conv_bf16(const float* __restrict__ src, unsigned short* __restrict__ dst, int n4) {
  int i = blockIdx.x * blockDim.x + threadIdx.x;
  if (i >= n4) return;
  const float4 v = ((const float4*)src)[i];
  ushort4 o; o.x = f2bf(v.x); o.y = f2bf(v.y); o.z = f2bf(v.z); o.w = f2bf(v.w);
  ((ushort4*)dst)[i] = o;
}

// ---------- embedding gather -> bf16 [4096][512] ----------
__global__ void gather_xe(const int* __restrict__ x, const float* __restrict__ emb,
                          unsigned short* __restrict__ xe) {
  const int m = blockIdx.x;              // b*256 + t
  const int tok = x[m];
  const float4 v = ((const float4*)(emb + (size_t)tok * 512))[threadIdx.x];
  ushort4 o; o.x = f2bf(v.x); o.y = f2bf(v.y); o.z = f2bf(v.z); o.w = f2bf(v.w);
  ((ushort4*)(xe + (size_t)m * 512))[threadIdx.x] = o;
}

// ---------- h0 = tanh(z @ W_init^T + b_init) ----------
__global__ __launch_bounds__(256) void h0_kernel(const float* __restrict__ z,
                                                 const float* __restrict__ Wi,
                                                 const float* __restrict__ bi,
                                                 float* __restrict__ h0f,
                                                 unsigned short* __restrict__ hb16) {
  const int idx = blockIdx.x * 256 + threadIdx.x;  // 0..16383
  const int b = idx & 15, i = idx >> 4;
  const float4* wr = (const float4*)(Wi + (size_t)i * 1024);
  const float4* zr = (const float4*)(z + (size_t)b * 1024);
  float acc = bi[i];
#pragma unroll 4
  for (int k = 0; k < 256; ++k) {
    float4 w = wr[k], zv = zr[k];
    acc += w.x * zv.x + w.y * zv.y + w.z * zv.z + w.w * zv.w;
  }
  const float h = tanh_(acc);
  h0f[(size_t)b * 1024 + i] = h;            // fp32 state init
  hb16[(size_t)b * 1024 + i] = f2bf(h);     // parity-0 exchange buffer (bf16)
}

// ---------- bf16 GEMM, C[M,N] = A[M,K] @ B[N,K]^T + bias ----------
template <typename OutT>
__global__ __launch_bounds__(256) void gemm_bt(
    const unsigned short* __restrict__ A, const unsigned short* __restrict__ Bm,
    const float* __restrict__ bias, OutT* __restrict__ C,
    int M, int N, int K) {
  __shared__ __align__(16) unsigned short As[128 * 32];
  __shared__ __align__(16) unsigned short Bs[128 * 32];
  const int tid = threadIdx.x;
  const int lane = tid & 63, wave = tid >> 6;
  const int nTM = M >> 7;
  const int bm = blockIdx.x % nTM, bn = blockIdx.x / nTM;
  const long row0 = (long)bm << 7, col0 = (long)bn << 7;
  const int wm = (wave & 1) << 6, wn = (wave >> 1) << 6;

  f32x4 acc[4][4] = {};

  const int sr = (wave << 4) + (lane >> 2);
  const int sk = (lane & 3) << 3;
  const unsigned short* Abase = A + ((size_t)(row0 + sr)) * K + sk;
  const unsigned short* Bbase = Bm + ((size_t)(col0 + sr)) * K + sk;
  char* ldsA = (char*)As + wave * 1024;
  char* ldsB = (char*)Bs + wave * 1024;

  for (int k0 = 0; k0 < K; k0 += 32) {
    __syncthreads();
    GLDS(Abase + k0, ldsA);
    GLDS(Abase + (size_t)64 * K + k0, ldsA + 4096);
    GLDS(Bbase + k0, ldsB);
    GLDS(Bbase + (size_t)64 * K + k0, ldsB + 4096);
    __syncthreads();
    const int lr = lane & 15, lk = (lane >> 4) << 3;
    bf16x8 af[4], bfr[4];
#pragma unroll
    for (int i = 0; i < 4; ++i) {
      af[i]  = *(const bf16x8*)(As + (wm + i * 16 + lr) * 32 + lk);
      bfr[i] = *(const bf16x8*)(Bs + (wn + i * 16 + lr) * 32 + lk);
    }
#pragma unroll
    for (int i = 0; i < 4; ++i)
#pragma unroll
      for (int j = 0; j < 4; ++j)
        acc[i][j] = __builtin_amdgcn_mfma_f32_16x16x32_bf16(af[i], bfr[j], acc[i][j], 0, 0, 0);
  }

  const int lr = lane & 15, lq = (lane >> 4) << 2;
#pragma unroll
  for (int i = 0; i < 4; ++i) {
#pragma unroll
    for (int q = 0; q < 4; ++q) {
      const long r = row0 + wm + i * 16 + lq + q;
      OutT* crow = C + (size_t)r * N;
#pragma unroll
      for (int j = 0; j < 4; ++j) {
        const long cc = col0 + wn + j * 16 + lr;
        float v = acc[i][j][q] + bias[cc];
        if constexpr (sizeof(OutT) == 2) crow[cc] = (OutT)f2bf(v);
        else                             crow[cc] = (OutT)v;
      }
    }
  }
}

// ---------- persistent GRU recurrence ----------
// 64 blocks x 256 thr. Block j owns h cols [16j,16j+16); 48 W_hh rows in
// registers (bf16 fragments). Exchange: bf16 h parity buffers via explicit
// sc0|sc1 wide loads/stores (write-through, coherent, NO compiler fences).
// Release = wave0 vmcnt(0) + relaxed flag store. Acquire = relaxed flag poll.
__global__ __launch_bounds__(256) void gru_rec(
    const float* __restrict__ Whh, const float* __restrict__ bhh,
    const unsigned short* __restrict__ gi, const float* __restrict__ h0f,
    unsigned short* __restrict__ hb16, unsigned short* __restrict__ hs,
    unsigned int* __restrict__ flags) {
  __shared__ float ghp[4][16][48];              // 12 KB partials
  __shared__ unsigned short hsl[16][16];        // 512 B staging of new h slice
  const int tid = threadIdx.x, lane = tid & 63, wave = tid >> 6;
  const int j = blockIdx.x;

  const int lr = lane & 15;            // A row (batch) / B row-within-tile
  const int hi8 = (lane >> 4) << 3;    // k-octet offset
  const int kw = wave << 8;            // 256 k per wave

  // ---- load W_hh slice into registers (bf16 fragments), once ----
  bf16x8 wf[3][8];
#pragma unroll
  for (int n = 0; n < 3; ++n) {
    const float* wrow = Whh + (size_t)(n * 1024 + (j << 4) + lr) * 1024 + kw + hi8;
#pragma unroll
    for (int ki = 0; ki < 8; ++ki) {
      const float4 u = *(const float4*)(wrow + ki * 32);
      const float4 v = *(const float4*)(wrow + ki * 32 + 4);
      bf16x8 w;
      w[0] = (short)f2bf(u.x); w[1] = (short)f2bf(u.y);
      w[2] = (short)f2bf(u.z); w[3] = (short)f2bf(u.w);
      w[4] = (short)f2bf(v.x); w[5] = (short)f2bf(v.y);
      w[6] = (short)f2bf(v.z); w[7] = (short)f2bf(v.w);
      wf[n][ki] = w;
    }
  }

  const int b = tid >> 4, c = tid & 15;
  const int cg = (j << 4) + c;
  float hreg = h0f[(size_t)b * 1024 + cg];
  const float br = bhh[cg], bz = bhh[1024 + cg], bn = bhh[2048 + cg];

  // prefetch gi for t=0
  const unsigned short* gr0 = gi + ((size_t)b * 256 + 0) * 3072;
  float ir = bf2f(gr0[cg]), iz = bf2f(gr0[1024 + cg]), inn = bf2f(gr0[2048 + cg]);

  for (int t = 0; t < 256; ++t) {
    if (t > 0) {
      if (tid < 64) {
        const unsigned tgt = (unsigned)t;
        long guard = 0;
        while (__hip_atomic_load(&flags[tid << 5], __ATOMIC_RELAXED, __HIP_MEMORY_SCOPE_AGENT) < tgt) {
          __builtin_amdgcn_s_sleep(1);
          if (++guard > (1L << 20)) break;   // hang guard (never hit if co-resident)
        }
      }
      __syncthreads();
    }

    // ---- A fragments: 8 coherent 16B loads (bf16 direct), one latency round ----
    const unsigned short* hrow = hb16 + ((t & 1) << 14) + (size_t)lr * 1024 + kw + hi8;
    i32x4 hv[8];
#pragma unroll
    for (int ki = 0; ki < 8; ++ki) hv[ki] = ld_coh_b128(hrow + (ki << 5));
    wait_vm0_fence();

    f32x4 acc[3] = {};
#pragma unroll
    for (int ki = 0; ki < 8; ++ki) {
      const bf16x8 af = __builtin_bit_cast(bf16x8, hv[ki]);
#pragma unroll
      for (int n = 0; n < 3; ++n)
        acc[n] = __builtin_amdgcn_mfma_f32_16x16x32_bf16(af, wf[n][ki], acc[n], 0, 0, 0);
    }
#pragma unroll
    for (int n = 0; n < 3; ++n)
#pragma unroll
      for (int q = 0; q < 4; ++q)
        ghp[wave][(lane >> 4) * 4 + q][n * 16 + lr] = acc[n][q];
    __syncthreads();

    // ---- gates (all 256 threads: thread = (b,c)) ----
    const float hr = ghp[0][b][c]      + ghp[1][b][c]      + ghp[2][b][c]      + ghp[3][b][c];
    const float hz = ghp[0][b][16 + c] + ghp[1][b][16 + c] + ghp[2][b][16 + c] + ghp[3][b][16 + c];
    const float hn = ghp[0][b][32 + c] + ghp[1][b][32 + c] + ghp[2][b][32 + c] + ghp[3][b][32 + c];
    const float rg = sigm(ir + hr + br);
    const float zg = sigm(iz + hz + bz);
    const float ng = tanh_(inn + rg * (hn + bn));
    const float hprev = hreg;
    hreg = (1.f - zg) * ng + zg * hprev;

    if (t < 255) {
      hsl[b][c] = f2bf(hreg);
      __syncthreads();                         // hsl complete
      unsigned short* hb_next = hb16 + (((t + 1) & 1) << 14);
      if (tid < 32) {                          // 32 x 16B coherent stores (all wave 0)
        const i32x4 v = *(const i32x4*)&hsl[tid >> 1][(tid & 1) << 3];
        st_coh_b128(hb_next + (size_t)(tid >> 1) * 1024 + (j << 4) + ((tid & 1) << 3), v);
      }
      if (wave == 0)                           // wave-uniform: drain wave0's stores
        asm volatile("s_waitcnt vmcnt(0)" ::: "memory");
      if (tid == 0)                            // relaxed: plain sc0|sc1 store, no wbl2
        __hip_atomic_store(&flags[j << 5], (unsigned)(t + 1),
                           __ATOMIC_RELAXED, __HIP_MEMORY_SCOPE_AGENT);
    }

    // off critical path: output h_t, prefetch gi for t+1
    hs[((size_t)b * 256 + t) * 1024 + cg] = f2bf(hprev);
    if (t < 255) {
      const unsigned short* gr = gi + ((size_t)b * 256 + (t + 1)) * 3072;
      ir = bf2f(gr[cg]); iz = bf2f(gr[1024 + cg]); inn = bf2f(gr[2048 + cg]);
    }
  }
}

// ---------- launch ----------
extern "C" void kernel_launch(void* const* d_in, const int* in_sizes, int n_in,
                              void* d_out, int out_size, void* d_ws, size_t ws_size,
                              hipStream_t stream) {
  const float* z     = (const float*)d_in[0];
  const int*   x     = (const int*)d_in[1];
  const float* emb   = (const float*)d_in[2];
  const float* Winit = (const float*)d_in[3];
  const float* binit = (const float*)d_in[4];
  const float* Wih   = (const float*)d_in[5];
  const float* Whh   = (const float*)d_in[6];
  const float* bih   = (const float*)d_in[7];
  const float* bhh   = (const float*)d_in[8];
  const float* Wout  = (const float*)d_in[9];
  const float* bout  = (const float*)d_in[10];
  float* out = (float*)d_out;

  char* ws = (char*)d_ws;
  size_t off = 0;
  auto alloc = [&](size_t bytes) { void* p = ws + off; off += (bytes + 255) & ~(size_t)255; return p; };
  unsigned int*   flags = (unsigned int*)alloc(64 * 128);
  unsigned short* xe    = (unsigned short*)alloc((size_t)4096 * 512 * 2);
  unsigned short* WihB  = (unsigned short*)alloc((size_t)3072 * 512 * 2);
  unsigned short* WoutB = (unsigned short*)alloc((size_t)32000 * 1024 * 2);
  unsigned short* giB   = (unsigned short*)alloc((size_t)4096 * 3072 * 2);
  unsigned short* hsB   = (unsigned short*)alloc((size_t)4096 * 1024 * 2);
  float*          h0f   = (float*)alloc((size_t)16 * 1024 * 4);
  unsigned short* hb16  = (unsigned short*)alloc((size_t)2 * 16 * 1024 * 2);
  (void)ws_size; (void)in_sizes; (void)n_in; (void)out_size;

  hipMemsetAsync(flags, 0, 64 * 128, stream);

  // weight conversions
  conv_bf16<<<dim3((3072 * 512 / 4 + 255) / 256), 256, 0, stream>>>(Wih, WihB, 3072 * 512 / 4);
  conv_bf16<<<dim3((32000 * 1024 / 4 + 255) / 256), 256, 0, stream>>>(Wout, WoutB, 32000 * 1024 / 4);

  // embeddings + h0
  gather_xe<<<dim3(4096), 128, 0, stream>>>(x, emb, xe);
  h0_kernel<<<dim3(64), 256, 0, stream>>>(z, Winit, binit, h0f, hb16);

  // gi = xe @ W_ih^T + b_ih   [4096, 3072] bf16
  gemm_bt<unsigned short><<<dim3(32 * 24), 256, 0, stream>>>(xe, WihB, bih, giB, 4096, 3072, 512);

  // GRU recurrence -> hs [4096, 1024] bf16
  gru_rec<<<dim3(64), 256, 0, stream>>>(Whh, bhh, giB, h0f, hb16, hsB, flags);

  // logits = hs @ W_out^T + b_out  [4096, 32000] fp32
  gemm_bt<float><<<dim3(32 * 250), 256, 0, stream>>>(hsB, WoutB, bout, out, 4096, 32000, 1024);
}